// Round 8
// baseline (1637.895 us; speedup 1.0000x reference)
//
#include <hip/hip_runtime.h>

// VectorQuantizer on MI355X (gfx950)
// z:   [B=128, C=128, H=32, W=32] f32 -> pixel n = b*1024 + hw, channel stride 1024
// emb: [K=256, C=128] f32
// out: [quantized_st 16777216][indices 131072][commit 1][codebook 1] (f32)
//
// Exactness contract (verified absmax=0 rounds 2-7 -- DO NOT CHANGE):
//   d_k = fl( fl(zz - 2*s_k) + ee_k )
//   s_k = sequential fmaf over c ascending; zz = sequential fl(z*z) sum
//   k ascending, first-occurrence argmin (u64 key: d_bits<<32 | k; d > 0 always)
//
// Round-8: same as round-7 (z in LDS once, 4-way k-split, KK=16) EXCEPT the
// e/ee path moves from s_load (SMEM, out-of-order -> forced lgkmcnt(0) drains
// around every ds_read) to per-lane global_load via opaque-VGPR base
// (vmcnt: counted waits, scheduler-pipelined, L2-broadcast).

typedef float f32x4 __attribute__((ext_vector_type(4)));

#define VQ_C      128
#define VQ_K      256
#define VQ_HW     1024
#define VQ_NPIX   131072
#define VQ_QELEMS 16777216
#define PXB       64                  // pixels per block
#define NBLK      (VQ_NPIX / PXB)     // 2048
#define KK        16                  // accumulators per chunk
#define KPQ       64                  // k's per thread (4-way split)
#define LROW      132                 // LDS row stride floats (read path bank-uniform)

// ws layout (floats): [0..255] ee[k]; [256..256+NBLK) per-block loss partials
__global__ void vq_prep(const float* __restrict__ emb, float* __restrict__ ws) {
    int k = threadIdx.x;               // 256 threads
    float s = 0.0f;
#pragma unroll
    for (int c = 0; c < VQ_C; ++c) {
        float e = emb[k * VQ_C + c];
        s = __fadd_rn(s, __fmul_rn(e, e));
    }
    ws[k] = s;
}

__global__ __launch_bounds__(256, 4) void vq_main(const float* __restrict__ z,
                                                  const float* __restrict__ emb,
                                                  const float* __restrict__ ee,
                                                  float* __restrict__ partials,
                                                  float* __restrict__ out) {
    __shared__ float              zf[PXB * LROW];   // 33792 B
    __shared__ unsigned long long key[4 * PXB];
    __shared__ float              red[4];

    const int t  = threadIdx.x;
    const int p  = t & 63;                     // pixel-in-block == lane
    const int q  = t >> 6;                     // wave id == k-quarter
    const int kbase = __builtin_amdgcn_readfirstlane(q * KPQ);
    const int n  = blockIdx.x * PXB + p;       // 64 | 1024 -> no b straddle
    const int b  = n >> 10;
    const int hw = n & 1023;
    const float* __restrict__ zb = z + (size_t)b * (VQ_C * VQ_HW) + hw;

    // Opaque zero in a VGPR: e/ee pointers formed from it are "divergent" to
    // the compiler -> global_load (vmcnt, counted waits), never s_load (lgkm).
    int vzero;
    asm volatile("v_mov_b32 %0, 0" : "=v"(vzero));
    const float* __restrict__ e0 = emb + vzero;
    const float* __restrict__ w0 = ee + vzero;

    // ---- stage z once: wave q loads c = q+4i (coalesced 256B per instr)
#pragma unroll
    for (int i = 0; i < 32; ++i) {
        int c = q + 4 * i;
        zf[p * LROW + c] = zb[c * VQ_HW];
    }
    __syncthreads();

    const f32x4* __restrict__ z4 = (const f32x4*)zf;   // index p*33 + cg

    float zz   = 0.0f;
    float dmin = INFINITY;
    int   imin = 0;

#pragma unroll 1
    for (int k0 = 0; k0 < KPQ; k0 += KK) {     // 4 chunks of 16 k's
        float acc[KK];
#pragma unroll
        for (int kk = 0; kk < KK; ++kk) acc[kk] = 0.0f;

#pragma unroll 4
        for (int cg = 0; cg < 32; ++cg) {      // 4 c's per iter
            f32x4 zv = z4[p * 33 + cg];        // ds_read_b128, bank-uniform

            if (k0 == 0) {                     // fold zz into chunk 0, c ascending
                zz = __fadd_rn(zz, __fmul_rn(zv[0], zv[0]));
                zz = __fadd_rn(zz, __fmul_rn(zv[1], zv[1]));
                zz = __fadd_rn(zz, __fmul_rn(zv[2], zv[2]));
                zz = __fadd_rn(zz, __fmul_rn(zv[3], zv[3]));
            }

#pragma unroll
            for (int kk = 0; kk < KK; ++kk) {
                // per-lane identical addr -> coalesced L2 broadcast, vmcnt path
                f32x4 ev = *(const f32x4*)(e0 + (kbase + k0 + kk) * VQ_C + cg * 4);
                acc[kk] = fmaf(zv[0], ev[0], acc[kk]);   // c ascending, exact
                acc[kk] = fmaf(zv[1], ev[1], acc[kk]);
                acc[kk] = fmaf(zv[2], ev[2], acc[kk]);
                acc[kk] = fmaf(zv[3], ev[3], acc[kk]);
            }
        }

#pragma unroll
        for (int kk = 0; kk < KK; ++kk) {
            float d = __fadd_rn(__fsub_rn(zz, __fadd_rn(acc[kk], acc[kk])),
                                w0[kbase + k0 + kk]);   // vmcnt path too
            if (d < dmin) { dmin = d; imin = kbase + k0 + kk; }  // strict <
        }
    }

    // ---- 4-way merge via u64 key (d>0 so bit order == float order;
    //      equal d -> lower index wins == first occurrence)
    union { float f; unsigned u; } du; du.f = dmin;
    key[q * PXB + p] = ((unsigned long long)du.u << 32) | (unsigned)imin;
    __syncthreads();
    unsigned long long kf = key[p];
#pragma unroll
    for (int j = 1; j < 4; ++j) {
        unsigned long long kj = key[j * PXB + p];
        if (kj < kf) kf = kj;
    }
    const int ifin = (int)(kf & 0xffffffffu);

    // ---- epilogue, c-split across q: thread (p,q) handles c in [q*32, q*32+32)
    const float* __restrict__ eq = emb + (size_t)ifin * VQ_C + q * 32;
    float* __restrict__ op = out + (size_t)b * (VQ_C * VQ_HW) + hw;
    float lsum = 0.0f;
#pragma unroll
    for (int cg = 0; cg < 8; ++cg) {
        f32x4 e4 = *(const f32x4*)(eq + cg * 4);       // divergent L2 gather
        f32x4 zv = z4[p * 33 + (q * 8 + cg)];          // exact z bits from LDS
#pragma unroll
        for (int j = 0; j < 4; ++j) {
            int c = q * 32 + cg * 4 + j;
            float diff = __fsub_rn(e4[j], zv[j]);
            op[c * VQ_HW] = __fadd_rn(zv[j], diff);    // coalesced per c
            lsum = fmaf(diff, diff, lsum);
        }
    }
    if (q == 0) out[VQ_QELEMS + n] = (float)ifin;

    // ---- loss partial: block reduce
#pragma unroll
    for (int off = 32; off > 0; off >>= 1) lsum += __shfl_down(lsum, off, 64);
    if ((t & 63) == 0) red[t >> 6] = lsum;
    __syncthreads();
    if (t == 0)
        partials[blockIdx.x] = (red[0] + red[1]) + (red[2] + red[3]);
}

__global__ void vq_fin(const float* __restrict__ partials, float* __restrict__ out) {
    double acc = 0.0;
    for (int i = 0; i < NBLK; ++i) acc += (double)partials[i];
    float m = (float)(acc * (1.0 / (double)VQ_QELEMS));
    out[VQ_QELEMS + VQ_NPIX + 0] = 0.25f * m;  // commitment
    out[VQ_QELEMS + VQ_NPIX + 1] = m;          // codebook
}

extern "C" void kernel_launch(void* const* d_in, const int* in_sizes, int n_in,
                              void* d_out, int out_size, void* d_ws, size_t ws_size,
                              hipStream_t stream) {
    const float* z   = (const float*)d_in[0];
    const float* emb = (const float*)d_in[1];
    float* out = (float*)d_out;
    float* ws  = (float*)d_ws;            // [0..255]=ee, [256..256+2048)=partials

    vq_prep<<<1, 256, 0, stream>>>(emb, ws);
    vq_main<<<NBLK, 256, 0, stream>>>(z, emb, ws, ws + 256, out);
    vq_fin<<<1, 1, 0, stream>>>(ws + 256, out);
}

// Round 9
// 513.059 us; speedup vs baseline: 3.1924x; 3.1924x over previous
//
#include <hip/hip_runtime.h>

// VectorQuantizer on MI355X (gfx950)
// z:   [B=128, C=128, H=32, W=32] f32 -> pixel n = b*1024 + hw, channel stride 1024
// emb: [K=256, C=128] f32
// out: [quantized_st 16777216][indices 131072][commit 1][codebook 1] (f32)
//
// Exactness contract (verified absmax=0 rounds 2-8 -- DO NOT CHANGE):
//   d_k = fl( fl(zz - 2*s_k) + ee_k )
//   s_k = sequential fmaf over c ascending; zz = sequential fl(z*z) sum
//   k ascending, first-occurrence argmin (u64 key: d_bits<<32 | k; d > 0 always)
//
// Round-9: round-7 structure (z in LDS once, 4-way k-split) with e/ee on the
// VMEM path (opaque-VGPR base -> global_load, vmcnt counted in-order waits;
// lgkm stays pure-DS) -- round 8's idea with register pressure CONTROLLED:
// KK=8, unroll 2 => ~105 VGPR, no spill (round 8: KK=16 x unroll4 spilled,
// 4.9GB scratch writes).

typedef float f32x4 __attribute__((ext_vector_type(4)));

#define VQ_C      128
#define VQ_K      256
#define VQ_HW     1024
#define VQ_NPIX   131072
#define VQ_QELEMS 16777216
#define PXB       64                  // pixels per block
#define NBLK      (VQ_NPIX / PXB)     // 2048
#define KK        8                   // accumulators per chunk (VGPR-sized)
#define KPQ       64                  // k's per thread (4-way split)
#define LROW      132                 // LDS row stride floats (read path bank-uniform)

// ws layout (floats): [0..255] ee[k]; [256..256+NBLK) per-block loss partials
__global__ void vq_prep(const float* __restrict__ emb, float* __restrict__ ws) {
    int k = threadIdx.x;               // 256 threads
    float s = 0.0f;
#pragma unroll
    for (int c = 0; c < VQ_C; ++c) {
        float e = emb[k * VQ_C + c];
        s = __fadd_rn(s, __fmul_rn(e, e));
    }
    ws[k] = s;
}

__global__ __launch_bounds__(256, 4) void vq_main(const float* __restrict__ z,
                                                  const float* __restrict__ emb,
                                                  const float* __restrict__ ee,
                                                  float* __restrict__ partials,
                                                  float* __restrict__ out) {
    __shared__ float              zf[PXB * LROW];   // 33792 B
    __shared__ unsigned long long key[4 * PXB];
    __shared__ float              red[4];

    const int t  = threadIdx.x;
    const int p  = t & 63;                     // pixel-in-block == lane
    const int q  = t >> 6;                     // wave id == k-quarter
    const int kbase = __builtin_amdgcn_readfirstlane(q * KPQ);
    const int n  = blockIdx.x * PXB + p;       // 64 | 1024 -> no b straddle
    const int b  = n >> 10;
    const int hw = n & 1023;
    const float* __restrict__ zb = z + (size_t)b * (VQ_C * VQ_HW) + hw;

    // Opaque zero in a VGPR: e/ee pointers formed from it are "divergent" to
    // the compiler -> global_load (vmcnt: in-order, counted waits), never
    // s_load (SMEM is out-of-order -> forces lgkmcnt(0) drains).
    int vzero;
    asm volatile("v_mov_b32 %0, 0" : "=v"(vzero));
    const float* __restrict__ e0 = emb + vzero;
    const float* __restrict__ w0 = ee + vzero;

    // ---- stage z once: wave q loads c = q+4i (coalesced 256B per instr)
#pragma unroll
    for (int i = 0; i < 32; ++i) {
        int c = q + 4 * i;
        zf[p * LROW + c] = zb[c * VQ_HW];
    }
    __syncthreads();

    const f32x4* __restrict__ z4 = (const f32x4*)zf;   // index p*33 + cg

    float zz   = 0.0f;
    float dmin = INFINITY;
    int   imin = 0;

#pragma unroll 1
    for (int k0 = 0; k0 < KPQ; k0 += KK) {     // 8 chunks of 8 k's
        float acc[KK];
#pragma unroll
        for (int kk = 0; kk < KK; ++kk) acc[kk] = 0.0f;

#pragma unroll 2
        for (int cg = 0; cg < 32; ++cg) {      // 4 c's per iter
            f32x4 zv = z4[p * 33 + cg];        // ds_read_b128 (lgkm: pure DS)

            if (k0 == 0) {                     // fold zz into chunk 0, c ascending
                zz = __fadd_rn(zz, __fmul_rn(zv[0], zv[0]));
                zz = __fadd_rn(zz, __fmul_rn(zv[1], zv[1]));
                zz = __fadd_rn(zz, __fmul_rn(zv[2], zv[2]));
                zz = __fadd_rn(zz, __fmul_rn(zv[3], zv[3]));
            }

            const float* __restrict__ ec = e0 + (kbase + k0) * VQ_C + cg * 4;
#pragma unroll
            for (int kk = 0; kk < KK; ++kk) {
                // identical addr across lanes -> 1 L2 line, broadcast; vmcnt path
                f32x4 ev = *(const f32x4*)(ec + kk * VQ_C);  // imm offset kk*512B
                acc[kk] = fmaf(zv[0], ev[0], acc[kk]);   // c ascending, exact
                acc[kk] = fmaf(zv[1], ev[1], acc[kk]);
                acc[kk] = fmaf(zv[2], ev[2], acc[kk]);
                acc[kk] = fmaf(zv[3], ev[3], acc[kk]);
            }
        }

#pragma unroll
        for (int kk = 0; kk < KK; ++kk) {
            float d = __fadd_rn(__fsub_rn(zz, __fadd_rn(acc[kk], acc[kk])),
                                w0[kbase + k0 + kk]);   // vmcnt path too
            if (d < dmin) { dmin = d; imin = kbase + k0 + kk; }  // strict <
        }
    }

    // ---- 4-way merge via u64 key (d>0 so bit order == float order;
    //      equal d -> lower index wins == first occurrence)
    union { float f; unsigned u; } du; du.f = dmin;
    key[q * PXB + p] = ((unsigned long long)du.u << 32) | (unsigned)imin;
    __syncthreads();
    unsigned long long kf = key[p];
#pragma unroll
    for (int j = 1; j < 4; ++j) {
        unsigned long long kj = key[j * PXB + p];
        if (kj < kf) kf = kj;
    }
    const int ifin = (int)(kf & 0xffffffffu);

    // ---- epilogue, c-split across q: thread (p,q) handles c in [q*32, q*32+32)
    //      (ifin is lane-divergent -> these stay genuine per-lane VMEM loads)
    const float* __restrict__ eq = emb + (size_t)ifin * VQ_C + q * 32;
    float* __restrict__ op = out + (size_t)b * (VQ_C * VQ_HW) + hw;
    float lsum = 0.0f;
#pragma unroll
    for (int cg = 0; cg < 8; ++cg) {
        f32x4 e4 = *(const f32x4*)(eq + cg * 4);       // divergent L2 gather
        f32x4 zv = z4[p * 33 + (q * 8 + cg)];          // exact z bits from LDS
#pragma unroll
        for (int j = 0; j < 4; ++j) {
            int c = q * 32 + cg * 4 + j;
            float diff = __fsub_rn(e4[j], zv[j]);
            op[c * VQ_HW] = __fadd_rn(zv[j], diff);    // coalesced per c
            lsum = fmaf(diff, diff, lsum);
        }
    }
    if (q == 0) out[VQ_QELEMS + n] = (float)ifin;

    // ---- loss partial: block reduce
#pragma unroll
    for (int off = 32; off > 0; off >>= 1) lsum += __shfl_down(lsum, off, 64);
    if ((t & 63) == 0) red[t >> 6] = lsum;
    __syncthreads();
    if (t == 0)
        partials[blockIdx.x] = (red[0] + red[1]) + (red[2] + red[3]);
}

__global__ void vq_fin(const float* __restrict__ partials, float* __restrict__ out) {
    double acc = 0.0;
    for (int i = 0; i < NBLK; ++i) acc += (double)partials[i];
    float m = (float)(acc * (1.0 / (double)VQ_QELEMS));
    out[VQ_QELEMS + VQ_NPIX + 0] = 0.25f * m;  // commitment
    out[VQ_QELEMS + VQ_NPIX + 1] = m;          // codebook
}

extern "C" void kernel_launch(void* const* d_in, const int* in_sizes, int n_in,
                              void* d_out, int out_size, void* d_ws, size_t ws_size,
                              hipStream_t stream) {
    const float* z   = (const float*)d_in[0];
    const float* emb = (const float*)d_in[1];
    float* out = (float*)d_out;
    float* ws  = (float*)d_ws;            // [0..255]=ee, [256..256+2048)=partials

    vq_prep<<<1, 256, 0, stream>>>(emb, ws);
    vq_main<<<NBLK, 256, 0, stream>>>(z, emb, ws, ws + 256, out);
    vq_fin<<<1, 1, 0, stream>>>(ws + 256, out);
}

// Round 10
// 292.544 us; speedup vs baseline: 5.5988x; 1.7538x over previous
//
#include <hip/hip_runtime.h>

// VectorQuantizer on MI355X (gfx950)
// z:   [B=128, C=128, H=32, W=32] f32 -> pixel n = b*1024 + hw, channel stride 1024
// emb: [K=256, C=128] f32
// out: [quantized_st 16777216][indices 131072][commit 1][codebook 1] (f32)
//
// Exactness contract (verified absmax=0 rounds 2-9 -- DO NOT CHANGE):
//   d_k = fl( fl(zz - 2*s_k) + ee_k )
//   s_k = sequential fmaf over c ascending; zz = sequential fl(z*z) sum
//   first-occurrence argmin == min over u64 keys (d_bits<<32 | k), d > 0
//
// Round-10: lane<->CODE mapping. 256 threads = 256 codes; 64 px/block in 4
// strips of 16 (acc[16]/thread). e via ONE coalesced per-lane dwordx4 per
// 4-channel step (pre-transposed eT2 in ws, L2-resident, vmcnt-pipelined);
// z wave-uniform -> scalar path; ee preloaded in 1 VGPR; zz via phase-A
// chain in LDS. 2048 blocks x tiny LDS -> ~6 waves/SIMD latency hiding.

typedef float f32x4 __attribute__((ext_vector_type(4)));
typedef unsigned long long u64;

#define VQ_C      128
#define VQ_K      256
#define VQ_HW     1024
#define VQ_CHW    (VQ_C * VQ_HW)
#define VQ_NPIX   131072
#define VQ_QELEMS 16777216
#define PXB       64
#define NBLK      (VQ_NPIX / PXB)        // 2048
// ws float layout (ET2): [0..32768) eT2; [32768..33024) ee; [33024..35072) partials
#define WS_ET2_FLOATS (32768 + 256 + 2048)

template <bool ET2>
__global__ void vq_prep(const float* __restrict__ emb, float* __restrict__ ws) {
    int k = threadIdx.x;                  // 256 threads = 256 codes
    float s = 0.0f;
#pragma unroll
    for (int c = 0; c < VQ_C; ++c) {
        float e = emb[k * VQ_C + c];
        s = __fadd_rn(s, __fmul_rn(e, e));
    }
    if (ET2) {
        // eT2[cq][k][j] = emb[k][4cq+j]: per-cq lanes write consecutive 16B -> coalesced
#pragma unroll
        for (int cq = 0; cq < 32; ++cq) {
            f32x4 v = *(const f32x4*)(emb + k * VQ_C + cq * 4);
            *(f32x4*)(ws + (cq * 256 + k) * 4) = v;
        }
        ws[32768 + k] = s;
    } else {
        ws[k] = s;
    }
}

template <bool ET2>
__global__ __launch_bounds__(256, 6) void vq_main(const float* __restrict__ z,
                                                  const float* __restrict__ emb,
                                                  const float* __restrict__ ws,
                                                  float* __restrict__ partials,
                                                  float* __restrict__ out) {
    __shared__ float zzs[PXB];
    __shared__ u64   wkey[4][16];
    __shared__ int   iminS[PXB];
    __shared__ float red[4];

    const int t    = threadIdx.x;
    const int lane = t & 63;
    const int q    = t >> 6;
    const int code = q * 64 + lane;            // thread's code, whole kernel
    const int n0   = blockIdx.x * PXB;
    const int b    = n0 >> 10;
    const int hw0  = n0 & 1023;                // multiple of 64
    const float* __restrict__ zblk = z + (size_t)b * VQ_CHW + hw0;  // +c*1024+px

    const float* __restrict__ eeArr = ET2 ? (ws + 32768) : ws;
    const float eec = eeArr[code];             // 1 VGPR, coalesced load

    // ---- phase A: zz per pixel, the exact sequential chain (wave 0 only)
    if (t < PXB) {
        float zz = 0.0f;
#pragma unroll
        for (int c = 0; c < VQ_C; ++c) {
            float v = zblk[c * VQ_HW + t];     // 64-lane coalesced per c
            zz = __fadd_rn(zz, __fmul_rn(v, v));
        }
        zzs[t] = zz;
    }
    __syncthreads();

    // ---- strips of 16 pixels
#pragma unroll 1
    for (int s = 0; s < 4; ++s) {
        const int px0 = s * 16;
        float acc[16];
#pragma unroll
        for (int p = 0; p < 16; ++p) acc[p] = 0.0f;

        const float* __restrict__ zs = zblk + px0;

#pragma unroll 1
        for (int cq = 0; cq < 32; ++cq) {      // 4 channels per iter
            f32x4 ev;                          // e[code][4cq..4cq+4): per-lane
            if (ET2) ev = *(const f32x4*)(ws + (cq * 256 + code) * 4);   // coalesced
            else     ev = *(const f32x4*)(emb + code * VQ_C + cq * 4);   // scatter

#pragma unroll
            for (int j = 0; j < 4; ++j) {      // c = 4cq+j ascending
                const float* zr = zs + (cq * 4 + j) * VQ_HW;   // uniform -> scalar
                f32x4 z0 = *(const f32x4*)(zr + 0);
                f32x4 z1 = *(const f32x4*)(zr + 4);
                f32x4 z2 = *(const f32x4*)(zr + 8);
                f32x4 z3 = *(const f32x4*)(zr + 12);
#pragma unroll
                for (int i = 0; i < 4; ++i) {
                    acc[i]      = fmaf(z0[i], ev[j], acc[i]);   // s_src * v_e
                    acc[4 + i]  = fmaf(z1[i], ev[j], acc[4 + i]);
                    acc[8 + i]  = fmaf(z2[i], ev[j], acc[8 + i]);
                    acc[12 + i] = fmaf(z3[i], ev[j], acc[12 + i]);
                }
            }
        }

        // ---- d + argmin reduce over codes, half-batches of 8 px (VGPR control)
#pragma unroll
        for (int h = 0; h < 2; ++h) {
            u64 key[8];
#pragma unroll
            for (int p = 0; p < 8; ++p) {
                float zz = zzs[px0 + h * 8 + p];           // LDS broadcast
                float a  = acc[h * 8 + p];
                float d  = __fadd_rn(__fsub_rn(zz, __fadd_rn(a, a)), eec);
                union { float f; unsigned u; } du; du.f = d;
                key[p] = ((u64)du.u << 32) | (unsigned)code;
            }
#pragma unroll
            for (int st = 1; st < 64; st <<= 1) {
#pragma unroll
                for (int p = 0; p < 8; ++p) {
                    u64 o = __shfl_xor(key[p], st, 64);
                    if (o < key[p]) key[p] = o;
                }
            }
            if (lane == 0) {                   // all lanes hold min; lane 0 writes
#pragma unroll
                for (int p = 0; p < 8; ++p) wkey[q][h * 8 + p] = key[p];
            }
        }
        __syncthreads();
        if (t < 16) {                          // cross-wave 4-way merge
            u64 k0 = wkey[0][t];
#pragma unroll
            for (int w = 1; w < 4; ++w) { u64 kw = wkey[w][t]; if (kw < k0) k0 = kw; }
            iminS[px0 + t] = (int)(k0 & 0xffffffffu);
        }
        __syncthreads();
    }

    // ---- epilogue: thread t -> pixel t&63, c-block t>>6 (32 channels)
    const int px = t & 63;
    const int cb = t >> 6;
    const int im = iminS[px];
    const float* __restrict__ eq = emb + (size_t)im * VQ_C + cb * 32;
    const float* __restrict__ zp = zblk + px;
    float* __restrict__ op = out + (size_t)b * VQ_CHW + hw0 + px;
    float lsum = 0.0f;
#pragma unroll
    for (int i = 0; i < 8; ++i) {
        f32x4 e4 = *(const f32x4*)(eq + i * 4);            // divergent L2 gather
#pragma unroll
        for (int j = 0; j < 4; ++j) {
            int c = cb * 32 + i * 4 + j;
            float zv   = zp[c * VQ_HW];                    // coalesced, exact bits
            float diff = __fsub_rn(e4[j], zv);
            op[c * VQ_HW] = __fadd_rn(zv, diff);           // coalesced per c
            lsum = fmaf(diff, diff, lsum);
        }
    }
    if (t < PXB) out[VQ_QELEMS + n0 + t] = (float)iminS[t];

    // ---- loss partial
#pragma unroll
    for (int off = 32; off > 0; off >>= 1) lsum += __shfl_down(lsum, off, 64);
    if ((t & 63) == 0) red[q] = lsum;
    __syncthreads();
    if (t == 0)
        partials[blockIdx.x] = (red[0] + red[1]) + (red[2] + red[3]);
}

__global__ void vq_fin(const float* __restrict__ partials, float* __restrict__ out) {
    double acc = 0.0;
    for (int i = 0; i < NBLK; ++i) acc += (double)partials[i];
    float m = (float)(acc * (1.0 / (double)VQ_QELEMS));
    out[VQ_QELEMS + VQ_NPIX + 0] = 0.25f * m;  // commitment
    out[VQ_QELEMS + VQ_NPIX + 1] = m;          // codebook
}

extern "C" void kernel_launch(void* const* d_in, const int* in_sizes, int n_in,
                              void* d_out, int out_size, void* d_ws, size_t ws_size,
                              hipStream_t stream) {
    const float* z   = (const float*)d_in[0];
    const float* emb = (const float*)d_in[1];
    float* out = (float*)d_out;
    float* ws  = (float*)d_ws;

    const bool et2 = ws_size >= (size_t)WS_ET2_FLOATS * sizeof(float);
    if (et2) {
        float* partials = ws + 33024;
        vq_prep<true><<<1, 256, 0, stream>>>(emb, ws);
        vq_main<true><<<NBLK, 256, 0, stream>>>(z, emb, ws, partials, out);
        vq_fin<<<1, 1, 0, stream>>>(partials, out);
    } else {
        float* partials = ws + 256;
        vq_prep<false><<<1, 256, 0, stream>>>(emb, ws);
        vq_main<false><<<NBLK, 256, 0, stream>>>(z, emb, ws, partials, out);
        vq_fin<<<1, 1, 0, stream>>>(partials, out);
    }
}

// Round 11
// 200.495 us; speedup vs baseline: 8.1693x; 1.4591x over previous
//
#include <hip/hip_runtime.h>

// VectorQuantizer on MI355X (gfx950)
// z:   [B=128, C=128, H=32, W=32] f32 -> pixel n = b*1024 + hw, channel stride 1024
// emb: [K=256, C=128] f32
// out: [quantized_st 16777216][indices 131072][commit 1][codebook 1] (f32)
//
// Exactness contract (verified absmax=0 rounds 2-10 -- DO NOT CHANGE):
//   d_k = fl( fl(zz - 2*s_k) + ee_k )
//   s_k = sequential fmaf over c ascending; zz = sequential fl(z*z) sum
//   first-occurrence argmin == min over u64 keys (d_bits<<32 | k), d > 0
//
// Round-11: classic GEMM register tile. Block = 64 px x 256 codes, thread
// tile 8px x 8codes (acc[8][8], fully static). BOTH operands from LDS via
// ds_read_b128 (pure-DS lgkm -> counted waits; no SMEM in hot loop):
//   z tile [c][px] -> reads are 2-address broadcasts (free)
//   e tile XOR-swizzled (c4*16)^(((code>>3)&7)*16) -> <=4-way
// Per 4-c window: 16 LDS reads + 256 FMA (512 cyc) => FMA-bound.

typedef float f32x4 __attribute__((ext_vector_type(4)));
typedef unsigned long long u64;

#define VQ_C      128
#define VQ_K      256
#define VQ_HW     1024
#define VQ_CHW    (VQ_C * VQ_HW)
#define VQ_NPIX   131072
#define VQ_QELEMS 16777216
#define PXB       64
#define NBLK      (VQ_NPIX / PXB)     // 2048
#define CCH       32                  // channels per chunk
#define NCH       4

// ws layout (floats): [0..255] ee[k]; [256..256+NBLK) per-block loss partials
__global__ void vq_prep(const float* __restrict__ emb, float* __restrict__ ws) {
    int k = threadIdx.x;               // 256 threads = 256 codes
    float s = 0.0f;
#pragma unroll
    for (int c = 0; c < VQ_C; ++c) {
        float e = emb[k * VQ_C + c];
        s = __fadd_rn(s, __fmul_rn(e, e));
    }
    ws[k] = s;
}

__global__ __launch_bounds__(256, 3) void vq_main(const float* __restrict__ z,
                                                  const float* __restrict__ emb,
                                                  const float* __restrict__ ee,
                                                  float* __restrict__ partials,
                                                  float* __restrict__ out) {
    __shared__ float zs[CCH * PXB];        // [c][px], 8 KB
    __shared__ char  es[VQ_K * CCH * 4];   // swizzled e tile, 32 KB
    __shared__ float zzs[PXB];
    __shared__ int   iminS[PXB];
    __shared__ float red[4];

    const int tx = threadIdx.x;
    const int cg = tx & 31;                // code group: codes cg*8 .. +8
    const int pg = tx >> 5;                // px group:  px  pg*8 .. +8
    const int n0 = blockIdx.x * PXB;
    const int b  = n0 >> 10;
    const int hw0 = n0 & 1023;             // 64 | 1024 -> no b straddle
    const float* __restrict__ zb = z + (size_t)b * VQ_CHW + hw0;

    // ---- phase A: zz per pixel, exact sequential chain (wave 0; covered by
    //      the first post-staging barrier)
    if (tx < PXB) {
        float zz = 0.0f;
#pragma unroll
        for (int c = 0; c < VQ_C; ++c) {
            float v = zb[c * VQ_HW + tx];  // 64-lane coalesced per c
            zz = __fadd_rn(zz, __fmul_rn(v, v));
        }
        zzs[tx] = zz;
    }

    float acc[8][8];
#pragma unroll
    for (int p = 0; p < 8; ++p)
#pragma unroll
        for (int o = 0; o < 8; ++o) acc[p][o] = 0.0f;

    const int ci = tx >> 6;                // z-staging c-lane (wave id)
    const int px = tx & 63;

#pragma unroll 1
    for (int ch = 0; ch < NCH; ++ch) {
        const int c0 = ch * CCH;
        if (ch) __syncthreads();           // protect tiles from overwrite

        // ---- stage z tile [c][px]: coalesced global reads, free LDS writes
#pragma unroll
        for (int i = 0; i < 8; ++i) {
            int c = i * 4 + ci;
            zs[c * PXB + px] = zb[(c0 + c) * VQ_HW + px];
        }
        // ---- stage e tile: thread tx = code; L2-hot gather + swizzled write
        {
            const float* __restrict__ eg = emb + tx * VQ_C + c0;
#pragma unroll
            for (int c4 = 0; c4 < 8; ++c4) {
                f32x4 v = *(const f32x4*)(eg + c4 * 4);
                int sw = (c4 * 16) ^ (((tx >> 3) & 7) * 16);
                *(f32x4*)(es + tx * 128 + sw) = v;
            }
        }
        __syncthreads();

        // ---- compute: 8 windows of 4 channels
#pragma unroll 1
        for (int c4 = 0; c4 < 8; ++c4) {
            f32x4 zf[4][2];                // [j][half]: 8 px of channel c4*4+j
#pragma unroll
            for (int j = 0; j < 4; ++j) {
                int c = c4 * 4 + j;
                zf[j][0] = *(const f32x4*)(zs + c * PXB + pg * 8);
                zf[j][1] = *(const f32x4*)(zs + c * PXB + pg * 8 + 4);
            }
            f32x4 ef[8];                   // 8 codes x 4 channels
#pragma unroll
            for (int o = 0; o < 8; ++o) {
                int code = cg * 8 + o;
                int sw = (c4 * 16) ^ (((code >> 3) & 7) * 16);
                ef[o] = *(const f32x4*)(es + code * 128 + sw);
            }
            // c ascending (j outer) => exact per-(px,code) fmaf chain
#pragma unroll
            for (int j = 0; j < 4; ++j)
#pragma unroll
                for (int o = 0; o < 8; ++o) {
                    float ev = ef[o][j];
#pragma unroll
                    for (int h = 0; h < 2; ++h)
#pragma unroll
                        for (int i = 0; i < 4; ++i)
                            acc[h * 4 + i][o] =
                                fmaf(zf[j][h][i], ev, acc[h * 4 + i][o]);
                }
        }
    }

    // ---- d + first-occurrence argmin (u64 keys; d > 0 so bit order = value order)
    float eev[8];
#pragma unroll
    for (int o = 0; o < 8; ++o) eev[o] = ee[cg * 8 + o];

#pragma unroll
    for (int p = 0; p < 8; ++p) {
        float zz = zzs[pg * 8 + p];
        u64 key = ~0ull;
#pragma unroll
        for (int o = 0; o < 8; ++o) {
            float a = acc[p][o];
            float d = __fadd_rn(__fsub_rn(zz, __fadd_rn(a, a)), eev[o]);
            union { float f; unsigned u; } du; du.f = d;
            u64 k2 = ((u64)du.u << 32) | (unsigned)(cg * 8 + o);
            if (k2 < key) key = k2;
        }
        // reduce across the 32 code-group threads (one half-wave)
#pragma unroll
        for (int st = 1; st < 32; st <<= 1) {
            u64 o2 = __shfl_xor(key, st, 32);
            if (o2 < key) key = o2;
        }
        if (cg == 0) iminS[pg * 8 + p] = (int)(key & 0xffffffffu);
    }
    __syncthreads();

    // ---- epilogue: thread -> pixel tx&63, channel-block tx>>6 (32 channels)
    const int cb = tx >> 6;
    const int im = iminS[px];
    const float* __restrict__ eq = emb + (size_t)im * VQ_C + cb * 32;
    const float* __restrict__ zp = zb + px;
    float* __restrict__ op = out + (size_t)b * VQ_CHW + hw0 + px;
    float lsum = 0.0f;
#pragma unroll
    for (int i = 0; i < 8; ++i) {
        f32x4 e4 = *(const f32x4*)(eq + i * 4);        // divergent L2 gather
#pragma unroll
        for (int j = 0; j < 4; ++j) {
            int c = cb * 32 + i * 4 + j;
            float zv   = zp[c * VQ_HW];                // L2-hot, exact bits
            float diff = __fsub_rn(e4[j], zv);
            op[c * VQ_HW] = __fadd_rn(zv, diff);       // coalesced per c
            lsum = fmaf(diff, diff, lsum);
        }
    }
    if (tx < PXB) out[VQ_QELEMS + n0 + tx] = (float)iminS[tx];

    // ---- loss partial
#pragma unroll
    for (int off = 32; off > 0; off >>= 1) lsum += __shfl_down(lsum, off, 64);
    if ((tx & 63) == 0) red[tx >> 6] = lsum;
    __syncthreads();
    if (tx == 0)
        partials[blockIdx.x] = (red[0] + red[1]) + (red[2] + red[3]);
}

__global__ void vq_fin(const float* __restrict__ partials, float* __restrict__ out) {
    double acc = 0.0;
    for (int i = 0; i < NBLK; ++i) acc += (double)partials[i];
    float m = (float)(acc * (1.0 / (double)VQ_QELEMS));
    out[VQ_QELEMS + VQ_NPIX + 0] = 0.25f * m;  // commitment
    out[VQ_QELEMS + VQ_NPIX + 1] = m;          // codebook
}

extern "C" void kernel_launch(void* const* d_in, const int* in_sizes, int n_in,
                              void* d_out, int out_size, void* d_ws, size_t ws_size,
                              hipStream_t stream) {
    const float* z   = (const float*)d_in[0];
    const float* emb = (const float*)d_in[1];
    float* out = (float*)d_out;
    float* ws  = (float*)d_ws;            // [0..255]=ee, [256..)=partials

    vq_prep<<<1, 256, 0, stream>>>(emb, ws);
    vq_main<<<NBLK, 256, 0, stream>>>(z, emb, ws, ws + 256, out);
    vq_fin<<<1, 1, 0, stream>>>(ws + 256, out);
}